// Round 2
// baseline (217.625 us; speedup 1.0000x reference)
//
#include <hip/hip_runtime.h>
#include <math.h>

namespace {
constexpr int SG = 14;
constexpr int NIMG = 4096;
constexpr int NCELLS = NIMG * SG * SG;   // 802816 = 3136 blocks * 256
constexpr int CPB = 256;                 // cells per block
constexpr int PAD = 31;                  // LDS stride per cell (odd -> conflict-free)
constexpr float STEPF = 1.0f / 14.0f;
constexpr float EPSF = 1e-6f;
constexpr float L_COORD = 7.0f;
constexpr float L_NOOBJ = 0.2f;
constexpr float L_CLS = 1.5f;
constexpr float INV_N = 1.0f / 4096.0f;
constexpr float FOUR_OVER_PI2 = 4.0f / (float)(M_PI * M_PI);
}

struct Box { float x1, y1, x2, y2; };

__device__ __forceinline__ float iou_fn(const Box& a, const Box& b) {
  float ix1 = fmaxf(a.x1, b.x1);
  float iy1 = fmaxf(a.y1, b.y1);
  float ix2 = fminf(a.x2, b.x2);
  float iy2 = fminf(a.y2, b.y2);
  float inter = fmaxf(ix2 - ix1, 0.0f) * fmaxf(iy2 - iy1, 0.0f);
  float a1 = (a.x2 - a.x1) * (a.y2 - a.y1);
  float a2 = (b.x2 - b.x1) * (b.y2 - b.y1);
  return inter / (a1 + a2 - inter + EPSF);
}

__global__ __launch_bounds__(256) void yolo_loss_kernel(
    const float* __restrict__ pred, const float* __restrict__ tgt,
    float* __restrict__ out) {
  __shared__ float lp[CPB * PAD];   // 31744 B
  __shared__ float lt[CPB * PAD];   // 31744 B  (total 62 KB -> 2 blocks/CU)

  const int tid = threadIdx.x;

  // ---- coalesced global -> LDS staging ----
  // Block owns 256*30 = 7680 floats = 3840 float2 per input. Lane-linear:
  // lane reads float2 #(j*256+tid) -> 512 B/wave/instr, fully coalesced.
  {
    const float2* P2 = reinterpret_cast<const float2*>(pred) + (size_t)blockIdx.x * (CPB * 30 / 2);
    const float2* T2 = reinterpret_cast<const float2*>(tgt)  + (size_t)blockIdx.x * (CPB * 30 / 2);
#pragma unroll
    for (int j = 0; j < 15; ++j) {
      const int idx = j * 256 + tid;       // float2 index within block, 0..3839
      const int f = idx * 2;               // flat float index (even)
      const int c = f / 30;                // cell
      const int e = f - 30 * c;            // element (even, e+1 <= 29)
      const float2 v = P2[idx];
      lp[c * PAD + e] = v.x; lp[c * PAD + e + 1] = v.y;
      const float2 u = T2[idx];
      lt[c * PAD + e] = u.x; lt[c * PAD + e + 1] = u.y;
    }
  }
  __syncthreads();

  // ---- per-cell compute; reads lds[tid*31 + k] -> stride 31 = conflict-free ----
  float p[30], t[30];
#pragma unroll
  for (int k = 0; k < 30; ++k) { p[k] = lp[tid * PAD + k]; t[k] = lt[tid * PAD + k]; }

  const int cell = blockIdx.x * CPB + tid;
  const int rem = cell % (SG * SG);
  const float gx = (float)(rem % SG);   // xg varies along last spatial dim (j)
  const float gy = (float)(rem / SG);   // yg varies along first spatial dim (i)

  Box pa0, pa1, ta0, ta1;
  {
    float cx = (p[0] + gx) * STEPF, cy = (p[1] + gy) * STEPF, w = p[2], h = p[3];
    pa0 = {cx - 0.5f * w, cy - 0.5f * h, cx + 0.5f * w, cy + 0.5f * h};
    cx = (p[5] + gx) * STEPF; cy = (p[6] + gy) * STEPF; w = p[7]; h = p[8];
    pa1 = {cx - 0.5f * w, cy - 0.5f * h, cx + 0.5f * w, cy + 0.5f * h};
    cx = (t[0] + gx) * STEPF; cy = (t[1] + gy) * STEPF; w = t[2]; h = t[3];
    ta0 = {cx - 0.5f * w, cy - 0.5f * h, cx + 0.5f * w, cy + 0.5f * h};
    cx = (t[5] + gx) * STEPF; cy = (t[6] + gy) * STEPF; w = t[7]; h = t[8];
    ta1 = {cx - 0.5f * w, cy - 0.5f * h, cx + 0.5f * w, cy + 0.5f * h};
  }

  // responsibility: both pred boxes vs TARGET BOX 0; argmax first-wins
  const float iou0 = iou_fn(pa0, ta0);
  const float iou1 = iou_fn(pa1, ta0);
  const bool m1 = iou1 > iou0;
  const bool obj0 = (t[4] > 0.0f) && !m1;
  const bool obj1 = (t[9] > 0.0f) && m1;
  const bool sig = obj0 || obj1;

  const float d0 = p[4] - t[4], d1 = p[9] - t[9];
  const float se0 = d0 * d0, se1 = d1 * d1;
  const float obj_loss   = (obj0 ? se0 : 0.0f) + (obj1 ? se1 : 0.0f);
  const float noobj_loss = (obj0 ? 0.0f : se0) + (obj1 ? 0.0f : se1);

  // CIoU for the responsible pairing (pred box mi vs target box mi)
  Box b1, b2;
  b1.x1 = m1 ? pa1.x1 : pa0.x1; b1.y1 = m1 ? pa1.y1 : pa0.y1;
  b1.x2 = m1 ? pa1.x2 : pa0.x2; b1.y2 = m1 ? pa1.y2 : pa0.y2;
  b2.x1 = m1 ? ta1.x1 : ta0.x1; b2.y1 = m1 ? ta1.y1 : ta0.y1;
  b2.x2 = m1 ? ta1.x2 : ta0.x2; b2.y2 = m1 ? ta1.y2 : ta0.y2;

  float bbox;
  {
    const float iou = iou_fn(b1, b2);
    const float cx1 = 0.5f * (b1.x1 + b1.x2), cy1 = 0.5f * (b1.y1 + b1.y2);
    const float cx2 = 0.5f * (b2.x1 + b2.x2), cy2 = 0.5f * (b2.y1 + b2.y2);
    const float cd = (cx1 - cx2) * (cx1 - cx2) + (cy1 - cy2) * (cy1 - cy2);
    const float ox1 = fminf(b1.x1, b2.x1), oy1 = fminf(b1.y1, b2.y1);
    const float ox2 = fmaxf(b1.x2, b2.x2), oy2 = fmaxf(b1.y2, b2.y2);
    const float od = (ox2 - ox1) * (ox2 - ox1) + (oy2 - oy1) * (oy2 - oy1) + EPSF;
    const float w1 = fmaxf(b1.x2 - b1.x1, EPSF), h1 = fmaxf(b1.y2 - b1.y1, EPSF);
    const float w2 = fmaxf(b2.x2 - b2.x1, EPSF), h2 = fmaxf(b2.y2 - b2.y1, EPSF);
    const float dat = atanf(w2 / h2) - atanf(w1 / h1);
    const float v = FOUR_OVER_PI2 * dat * dat;
    const float alpha = v / (1.0f - iou + v + EPSF);
    const float ciou = iou - cd / od - alpha * v;
    const float scale = fmaxf(2.0f - w2 * h2, 1.0f);
    bbox = sig ? (1.0f - ciou) * scale : 0.0f;
  }

  // class BCE (20 classes); clip(log, -100) is lower-only
  float cls = 0.0f;
#pragma unroll
  for (int k = 10; k < 30; ++k) {
    const float pc = p[k], tc = t[k];
    const float lp_  = fmaxf(logf(pc), -100.0f);
    const float l1mp = fmaxf(log1pf(-pc), -100.0f);
    cls += -(tc * lp_ + (1.0f - tc) * l1mp);
  }

  float acc = obj_loss + L_NOOBJ * noobj_loss + L_COORD * bbox
            + (sig ? L_CLS * cls : 0.0f);

  // reduction: wave64 shuffle -> LDS -> one atomic per block
#pragma unroll
  for (int off = 32; off > 0; off >>= 1) acc += __shfl_down(acc, off);

  __shared__ float sdata[4];
  const int lane = tid & 63;
  const int wid  = tid >> 6;
  if (lane == 0) sdata[wid] = acc;
  __syncthreads();
  if (tid == 0) {
    const float s = sdata[0] + sdata[1] + sdata[2] + sdata[3];
    atomicAdd(out, s * INV_N);
  }
}

extern "C" void kernel_launch(void* const* d_in, const int* in_sizes, int n_in,
                              void* d_out, int out_size, void* d_ws, size_t ws_size,
                              hipStream_t stream) {
  const float* pred = (const float*)d_in[0];
  const float* tgt  = (const float*)d_in[1];
  float* out = (float*)d_out;

  // d_out is re-poisoned to 0xAA before every timed replay -> zero it here.
  hipMemsetAsync(out, 0, sizeof(float), stream);

  const int blocks = NCELLS / CPB;   // 3136
  yolo_loss_kernel<<<blocks, CPB, 0, stream>>>(pred, tgt, out);
}

// Round 3
// 207.550 us; speedup vs baseline: 1.0485x; 1.0485x over previous
//
#include <hip/hip_runtime.h>
#include <math.h>

namespace {
constexpr int SG = 14;
constexpr int NIMG = 4096;
constexpr int NCELLS = NIMG * SG * SG;   // 802816 = 3136 blocks * 256
constexpr int CPB = 256;                 // cells per block
constexpr int PAD = 31;                  // LDS floats per cell (odd -> conflict-free reads)
constexpr float STEPF = 1.0f / 14.0f;
constexpr float EPSF = 1e-6f;
constexpr float L_COORD = 7.0f;
constexpr float L_NOOBJ = 0.2f;
constexpr float L_CLS = 1.5f;
constexpr float INV_N = 1.0f / 4096.0f;
constexpr float FOUR_OVER_PI2 = 4.0f / (float)(M_PI * M_PI);
}

struct Box { float x1, y1, x2, y2; };

// fast IoU: denominator >= EPS > 0, fast divide OK (tolerance ~152 absolute)
__device__ __forceinline__ float iou_fn(const Box& a, const Box& b) {
  float ix1 = fmaxf(a.x1, b.x1);
  float iy1 = fmaxf(a.y1, b.y1);
  float ix2 = fminf(a.x2, b.x2);
  float iy2 = fminf(a.y2, b.y2);
  float inter = fmaxf(ix2 - ix1, 0.0f) * fmaxf(iy2 - iy1, 0.0f);
  float a1 = (a.x2 - a.x1) * (a.y2 - a.y1);
  float a2 = (b.x2 - b.x1) * (b.y2 - b.y1);
  return __fdividef(inter, a1 + a2 - inter + EPSF);
}

__global__ __launch_bounds__(256) void yolo_loss_kernel(
    const float* __restrict__ pred, const float* __restrict__ tgt,
    float* __restrict__ out) {
  // Single half-size buffer, reused: stage pred -> regs -> stage tgt over it.
  // 31744 B -> LDS allows 4-5 blocks/CU (VGPR will cap at ~4) vs 2 before.
  __shared__ float buf[CPB * PAD];
  __shared__ float sdata[4];

  const int tid = threadIdx.x;

  // ---- phase 1: stage PRED, coalesced lane-linear float2 ----
  // flat float2 idx -> cell c = idx/15, lds addr = c*31 + e = 2*idx + c
  {
    const float2* P2 = reinterpret_cast<const float2*>(pred) + (size_t)blockIdx.x * (CPB * 15);
#pragma unroll
    for (int j = 0; j < 15; ++j) {
      const int idx = j * 256 + tid;
      const int c = idx / 15;            // magic-mul
      const int addr = 2 * idx + c;
      const float2 v = P2[idx];
      buf[addr] = v.x; buf[addr + 1] = v.y;
    }
  }
  __syncthreads();

  float p[30];
#pragma unroll
  for (int k = 0; k < 30; ++k) p[k] = buf[tid * PAD + k];
  __syncthreads();   // everyone done reading pred before overwrite

  // ---- phase 2: stage TGT over the same buffer ----
  {
    const float2* T2 = reinterpret_cast<const float2*>(tgt) + (size_t)blockIdx.x * (CPB * 15);
#pragma unroll
    for (int j = 0; j < 15; ++j) {
      const int idx = j * 256 + tid;
      const int c = idx / 15;
      const int addr = 2 * idx + c;
      const float2 u = T2[idx];
      buf[addr] = u.x; buf[addr + 1] = u.y;
    }
  }
  __syncthreads();

  float tb[10];
#pragma unroll
  for (int k = 0; k < 10; ++k) tb[k] = buf[tid * PAD + k];

  const int cell = blockIdx.x * CPB + tid;
  const int rem = cell % (SG * SG);
  const float gx = (float)(rem % SG);   // xg varies along last spatial dim
  const float gy = (float)(rem / SG);   // yg varies along first spatial dim

  Box pa0, pa1, ta0, ta1;
  {
    float cx = (p[0] + gx) * STEPF, cy = (p[1] + gy) * STEPF, w = p[2], h = p[3];
    pa0 = {cx - 0.5f * w, cy - 0.5f * h, cx + 0.5f * w, cy + 0.5f * h};
    cx = (p[5] + gx) * STEPF; cy = (p[6] + gy) * STEPF; w = p[7]; h = p[8];
    pa1 = {cx - 0.5f * w, cy - 0.5f * h, cx + 0.5f * w, cy + 0.5f * h};
    cx = (tb[0] + gx) * STEPF; cy = (tb[1] + gy) * STEPF; w = tb[2]; h = tb[3];
    ta0 = {cx - 0.5f * w, cy - 0.5f * h, cx + 0.5f * w, cy + 0.5f * h};
    cx = (tb[5] + gx) * STEPF; cy = (tb[6] + gy) * STEPF; w = tb[7]; h = tb[8];
    ta1 = {cx - 0.5f * w, cy - 0.5f * h, cx + 0.5f * w, cy + 0.5f * h};
  }

  // responsibility: both pred boxes vs TARGET BOX 0; argmax first-wins
  const float iou0 = iou_fn(pa0, ta0);
  const float iou1 = iou_fn(pa1, ta0);
  const bool m1 = iou1 > iou0;
  const bool obj0 = (tb[4] > 0.0f) && !m1;
  const bool obj1 = (tb[9] > 0.0f) && m1;
  const bool sig = obj0 || obj1;

  const float d0 = p[4] - tb[4], d1 = p[9] - tb[9];
  const float se0 = d0 * d0, se1 = d1 * d1;
  const float obj_loss   = (obj0 ? se0 : 0.0f) + (obj1 ? se1 : 0.0f);
  const float noobj_loss = (obj0 ? 0.0f : se0) + (obj1 ? 0.0f : se1);

  // CIoU for the responsible pairing (pred box mi vs target box mi)
  Box b1, b2;
  b1.x1 = m1 ? pa1.x1 : pa0.x1; b1.y1 = m1 ? pa1.y1 : pa0.y1;
  b1.x2 = m1 ? pa1.x2 : pa0.x2; b1.y2 = m1 ? pa1.y2 : pa0.y2;
  b2.x1 = m1 ? ta1.x1 : ta0.x1; b2.y1 = m1 ? ta1.y1 : ta0.y1;
  b2.x2 = m1 ? ta1.x2 : ta0.x2; b2.y2 = m1 ? ta1.y2 : ta0.y2;

  float bbox;
  {
    const float iou = iou_fn(b1, b2);
    const float cx1 = 0.5f * (b1.x1 + b1.x2), cy1 = 0.5f * (b1.y1 + b1.y2);
    const float cx2 = 0.5f * (b2.x1 + b2.x2), cy2 = 0.5f * (b2.y1 + b2.y2);
    const float cd = (cx1 - cx2) * (cx1 - cx2) + (cy1 - cy2) * (cy1 - cy2);
    const float ox1 = fminf(b1.x1, b2.x1), oy1 = fminf(b1.y1, b2.y1);
    const float ox2 = fmaxf(b1.x2, b2.x2), oy2 = fmaxf(b1.y2, b2.y2);
    const float od = (ox2 - ox1) * (ox2 - ox1) + (oy2 - oy1) * (oy2 - oy1) + EPSF;
    const float w1 = fmaxf(b1.x2 - b1.x1, EPSF), h1 = fmaxf(b1.y2 - b1.y1, EPSF);
    const float w2 = fmaxf(b2.x2 - b2.x1, EPSF), h2 = fmaxf(b2.y2 - b2.y1, EPSF);
    const float dat = atanf(__fdividef(w2, h2)) - atanf(__fdividef(w1, h1));
    const float v = FOUR_OVER_PI2 * dat * dat;
    const float alpha = __fdividef(v, 1.0f - iou + v + EPSF);
    const float ciou = iou - __fdividef(cd, od) - alpha * v;
    const float scale = fmaxf(2.0f - w2 * h2, 1.0f);
    bbox = sig ? (1.0f - ciou) * scale : 0.0f;   // select AFTER: masks any NaN
  }

  // class BCE (20 classes); hardware v_log_f32 via __logf.
  // __logf(0) = -inf -> fmaxf(-inf,-100) = -100, matches jnp.clip(log, -100).
  float cls = 0.0f;
#pragma unroll
  for (int k = 0; k < 20; ++k) {
    const float pc = p[10 + k];
    const float tc = buf[tid * PAD + 10 + k];   // tgt classes straight from LDS
    const float lg   = fmaxf(__logf(pc), -100.0f);
    const float l1mp = fmaxf(__logf(1.0f - pc), -100.0f);
    cls += -(tc * lg + (1.0f - tc) * l1mp);
  }

  float acc = obj_loss + L_NOOBJ * noobj_loss + L_COORD * bbox
            + (sig ? L_CLS * cls : 0.0f);

  // reduction: wave64 shuffle -> LDS -> one atomic per block
#pragma unroll
  for (int off = 32; off > 0; off >>= 1) acc += __shfl_down(acc, off);

  const int lane = tid & 63;
  const int wid  = tid >> 6;
  if (lane == 0) sdata[wid] = acc;
  __syncthreads();
  if (tid == 0) {
    const float s = sdata[0] + sdata[1] + sdata[2] + sdata[3];
    atomicAdd(out, s * INV_N);
  }
}

extern "C" void kernel_launch(void* const* d_in, const int* in_sizes, int n_in,
                              void* d_out, int out_size, void* d_ws, size_t ws_size,
                              hipStream_t stream) {
  const float* pred = (const float*)d_in[0];
  const float* tgt  = (const float*)d_in[1];
  float* out = (float*)d_out;

  // d_out is re-poisoned to 0xAA before every timed replay -> zero it here.
  hipMemsetAsync(out, 0, sizeof(float), stream);

  const int blocks = NCELLS / CPB;   // 3136
  yolo_loss_kernel<<<blocks, CPB, 0, stream>>>(pred, tgt, out);
}